// Round 5
// baseline (85.782 us; speedup 1.0000x reference)
//
#include <hip/hip_runtime.h>

// MSDeformAttn sampling-weight scatter (RankDetr), bug-compatible with the
// reference's axis-mislabeled reshape: output column q' = m/48, m=(l*8+h)*300+q.
//
// Gather-style privatization. Output (S=22223, Q=300) tiled as (level-aligned
// row tiles) x (8-wide q' groups). One block per tile: zero LDS (float4) ->
// scan the q-group's samples for the tile's level(s), filter by tile rows,
// LDS-atomic the 4 bilinear corners -> coalesced write-out. Output written
// exactly once, no memset needed.
//
// Grid-granularity: 64.5 KB LDS => 2 blocks/CU => 512 resident slots.
// 13 tiles/qgroup x 38 qgroups = 494 blocks <= 512: no second scheduling
// round (the previous 532-block grid paid a ~2x tail for 20 leftover blocks).
// L2+L3 are merged into one tile (contiguous s-range 20900..22223, 1323 cells).
//
// LDS is ql-major sm[ql*MAXC + cell]: atomic banks = cell%32 (random, ~2-way
// = free per m136); write-out gathers are 2 lanes/bank (free).
//
// Static shapes: N=1, L=6, Q=300, H=8, Lv=4, P=4; TOT=230400 samples.
// spatial: (100,167),(50,84),(25,42),(13,21); lsi = 0,16700,20900,21950.

constexpr int NQ   = 300;
constexpr int QW   = 8;                  // q'-group width
constexpr int NG   = 38;                 // ceil(300/8)
constexpr int NTILES = 13;               // 9 (L0,R=12) + 3 (L1,R=24) + 1 (L2+L3 merged)
constexpr int MAXC = 2016;               // max cells: L0 12*167=2004, L1 24*84=2016, L2+3 1323
constexpr int BLK  = 512;

__global__ __launch_bounds__(BLK)
void msda_tiled(const float2* __restrict__ loc,   // (TOT,2) = (x=col frac, y=row frac)
                const float*  __restrict__ aw,    // (TOT,)
                float*        __restrict__ out) { // (S, NQ)
    __shared__ float sm[QW * MAXC];               // 64,512 B, ql-major

    const int b  = blockIdx.x;
    const int g  = b / NTILES;                    // q'-group 0..37
    const int tb = b % NTILES;                    // s-tile id

    // tile descriptor: s_begin (global s of first cell), cells, and the scan
    // sublist(s) {lv, rlo, rhi}. Merged tile (tb==12) scans lv=2 then lv=3.
    int lv0, r0t, nr, nsub;
    if (tb < 9)       { lv0 = 0; r0t = 12 * tb;       nr = min(12, 100 - r0t); nsub = 1; }
    else if (tb < 12) { lv0 = 1; r0t = 24 * (tb - 9); nr = min(24, 50  - r0t); nsub = 1; }
    else              { lv0 = 2; r0t = 0;             nr = 25;                 nsub = 2; }

    const int Wlv_[4] = {167, 84, 42, 21};
    const int Hlv_[4] = {100, 50, 25, 13};
    const int lsi_[4] = {0, 16700, 20900, 21950};

    const int s_begin = lsi_[lv0] + r0t * Wlv_[lv0];
    const int cells   = (tb < 12) ? nr * Wlv_[lv0] : 1323;   // L2(1050)+L3(273)
    const int g0   = g * QW;
    const int qw   = min(QW, NQ - g0);            // 8, or 4 for the last group
    const int tid  = threadIdx.x;

    // zero the used LDS rows (qw full rows), float4 stores
    {
        const int nz = qw * MAXC / 4;
        float4* sm4 = (float4*)sm;
        for (int i = tid; i < nz; i += BLK) sm4[i] = make_float4(0.f, 0.f, 0.f, 0.f);
    }
    __syncthreads();

    // scan: for each sub-level, samples m in [48*g0, 48*g0+48*qw), p in [0,4)
    const int nm4 = 48 * qw * 4;                  // 1536 (768 last group)
    const int m0  = 48 * g0;

    for (int sub = 0; sub < nsub; ++sub) {
        const int lv  = lv0 + sub;
        const int W   = Wlv_[lv];
        const int rlo = (nsub == 1) ? r0t : 0;
        const int rhi = (nsub == 1) ? (r0t + nr) : Hlv_[lv];
        const int cbase = lsi_[lv] - s_begin;     // cell = cbase + r*W + c
        const float fW = (float)W, fH = (float)Hlv_[lv];

        for (int i = tid; i < nm4; i += BLK) {
            const int mi = i >> 2, p = i & 3;
            const int m  = m0 + mi;
            const int ql = mi / 48;               // local q' index in [0, qw)
            const int l  = m / 2400;
            const int rem = m - l * 2400;
            const int h  = rem / 300;
            const int q  = rem - h * 300;
            const int t  = (((l * 300 + q) * 8 + h) * 4 + lv) * 4 + p;

            const float2 xy = loc[t];
            const float  w  = aw[t];

            const float cf  = xy.x * fW;
            const float rf  = xy.y * fH;
            const float cfl = floorf(cf), rfl = floorf(rf);
            const float fc  = cf - cfl, fr = rf - rfl;
            const int c0 = (int)cfl, rr = (int)rfl;
            const int c1 = c0 + 1, r1 = rr + 1;

            const bool cv0 = (unsigned)c0 < (unsigned)W;   // 0 <= c0 < W
            const bool cv1 = (unsigned)c1 < (unsigned)W;
            const bool rv0 = (rr >= rlo) & (rr < rhi);     // in-tile (implies 0<=r<H)
            const bool rv1 = (r1 >= rlo) & (r1 < rhi);

            const float omfc = 1.0f - fc, omfr = 1.0f - fr;
            float* smq = &sm[ql * MAXC + cbase];
            if (rv0) {
                const int ro = rr * W;
                if (cv0) atomicAdd(&smq[ro + c0], w * omfc * omfr);
                if (cv1) atomicAdd(&smq[ro + c1], w * fc   * omfr);
            }
            if (rv1) {
                const int ro = r1 * W;
                if (cv0) atomicAdd(&smq[ro + c0], w * omfc * fr);
                if (cv1) atomicAdd(&smq[ro + c1], w * fc   * fr);
            }
        }
    }
    __syncthreads();

    // write-out: s in [s_begin, s_begin+cells), q' in [g0, g0+qw).
    // One float4 global store per (cell, v); LDS gathers are 2 lanes/bank (free).
    const int nq4 = qw >> 2;                      // 2 (or 1 last group)
    for (int i = tid; i < cells * nq4; i += BLK) {
        const int cell = i / nq4;
        const int v    = i - cell * nq4;
        float4 val;
        val.x = sm[(v * 4 + 0) * MAXC + cell];
        val.y = sm[(v * 4 + 1) * MAXC + cell];
        val.z = sm[(v * 4 + 2) * MAXC + cell];
        val.w = sm[(v * 4 + 3) * MAXC + cell];
        *(float4*)&out[(s_begin + cell) * NQ + g0 + v * 4] = val;
    }
}

extern "C" void kernel_launch(void* const* d_in, const int* in_sizes, int n_in,
                              void* d_out, int out_size, void* d_ws, size_t ws_size,
                              hipStream_t stream) {
    const float2* loc = (const float2*)d_in[0];   // sampling_locations (fp32)
    const float*  aw  = (const float*)d_in[1];    // attention_weights  (fp32)
    float* out = (float*)d_out;

    msda_tiled<<<NG * NTILES, BLK, 0, stream>>>(loc, aw, out);
}

// Round 6
// 79.721 us; speedup vs baseline: 1.0760x; 1.0760x over previous
//
#include <hip/hip_runtime.h>

// MSDeformAttn sampling-weight scatter (RankDetr), bug-compatible with the
// reference's axis-mislabeled reshape: output column q' = m/48, m=(l*8+h)*300+q.
//
// Gather-style privatization. Output (S=22223, Q=300) tiled as (level-aligned
// row tiles) x (8-wide q' groups). One block per tile: zero LDS (float4) ->
// scan the q-group's samples for the tile's level, filter by tile rows,
// LDS-atomic the 4 bilinear corners -> coalesced write-out. Output written
// exactly once, no memset needed.
//
// Occupancy: LDS = 8*1280*4 = 40960 B exactly => 4 blocks/CU (4*40 KiB =
// 160 KiB pool), 4 x 8 waves = 32 waves/CU (max). __launch_bounds__(512,8)
// caps VGPRs at 64 so registers don't break it. Grid 38*21 = 798 <= 1024
// resident slots. (Previous 64.5 KB tiles gave only 16 waves/CU; the kernel
// is latency-bound, so occupancy is the lever.)
//
// Scan is one thread per mi: its 4 p-samples are contiguous in memory
// (t = 16m+4lv+p), so loads are 2x float4 (loc) + 1x float4 (aw) instead of
// 8 scalar loads — fewer memory instructions, issued back-to-back.
//
// LDS is ql-major sm[ql*MAXC + cell], MAXC%32==0: atomic bank = cell%32
// (random, ~2-way = free per m136); write-out gathers are 2 lanes/bank (free).
//
// Static shapes: N=1, L=6, Q=300, H=8, Lv=4, P=4; TOT=230400 samples.
// spatial: (100,167),(50,84),(25,42),(13,21); lsi = 0,16700,20900,21950.

constexpr int NQ   = 300;
constexpr int QW   = 8;                  // q'-group width
constexpr int NG   = 38;                 // ceil(300/8)
constexpr int NTILES = 21;               // 15 (L0,R=7) + 4 (L1,R=15) + 1 (L2) + 1 (L3)
constexpr int MAXC = 1280;               // cells cap: L0 7*167=1169, L1 15*84=1260, L2 1050
constexpr int BLK  = 512;

__global__ __launch_bounds__(BLK, 8)
void msda_tiled(const float4* __restrict__ loc4,  // sampling_locations as float4 (2 samples each)
                const float4* __restrict__ aw4,   // attention_weights as float4 (4 samples each)
                float*        __restrict__ out) { // (S, NQ)
    __shared__ float sm[QW * MAXC];               // 40,960 B, ql-major

    const int b  = blockIdx.x;
    const int g  = b / NTILES;                    // q'-group 0..37
    const int tb = b % NTILES;                    // s-tile id

    int lv, r0t, nr;
    if (tb < 15)      { lv = 0; r0t = 7  * tb;        nr = min(7,  100 - r0t); }
    else if (tb < 19) { lv = 1; r0t = 15 * (tb - 15); nr = min(15, 50  - r0t); }
    else if (tb < 20) { lv = 2; r0t = 0;              nr = 25; }
    else              { lv = 3; r0t = 0;              nr = 13; }

    const int Wlv_[4] = {167, 84, 42, 21};
    const int Hlv_[4] = {100, 50, 25, 13};
    const int lsi_[4] = {0, 16700, 20900, 21950};
    const int W    = Wlv_[lv];
    const int base = lsi_[lv];
    const int g0   = g * QW;
    const int qw   = min(QW, NQ - g0);            // 8, or 4 for the last group
    const int cells = nr * W;
    const int tid  = threadIdx.x;

    // zero the used LDS rows (qw full rows), float4 stores
    {
        const int nz = qw * (MAXC / 4);
        float4* sm4 = (float4*)sm;
        for (int i = tid; i < nz; i += BLK) sm4[i] = make_float4(0.f, 0.f, 0.f, 0.f);
    }
    __syncthreads();

    // scan: one thread per mi; mi in [0, 48*qw). m = 48*g0 + mi.
    // Sample flat index t = 16*m + 4*lv + p; the 4 p-samples are contiguous.
    const int nm  = 48 * qw;                      // 384 (192 last group)
    const int rlo = r0t, rhi = r0t + nr;
    const float fW = (float)W, fH = (float)Hlv_[lv];

    if (tid < nm) {
        const int mi = tid;
        const int m  = 48 * g0 + mi;
        const int ql = mi / 48;                   // local q' index in [0, qw)
        const int l  = m / 2400;
        const int rem = m - l * 2400;
        const int h  = rem / 300;
        const int q  = rem - h * 300;
        const int t  = (((l * 300 + q) * 8 + h) * 4 + lv) * 4;   // p=0 base

        // vector loads: loc[t..t+3] = 2x float4, aw[t..t+3] = 1x float4
        const float4 xy01 = loc4[(t >> 1) + 0];   // (x0,y0,x1,y1)
        const float4 xy23 = loc4[(t >> 1) + 1];   // (x2,y2,x3,y3)
        const float4 w4   = aw4[t >> 2];

        float* smq = &sm[ql * MAXC];

        #pragma unroll
        for (int p = 0; p < 4; ++p) {
            const float x = (p == 0) ? xy01.x : (p == 1) ? xy01.z : (p == 2) ? xy23.x : xy23.z;
            const float y = (p == 0) ? xy01.y : (p == 1) ? xy01.w : (p == 2) ? xy23.y : xy23.w;
            const float w = (p == 0) ? w4.x   : (p == 1) ? w4.y   : (p == 2) ? w4.z   : w4.w;

            const float cf  = x * fW;
            const float rf  = y * fH;
            const float cfl = floorf(cf), rfl = floorf(rf);
            const float fc  = cf - cfl, fr = rf - rfl;
            const int c0 = (int)cfl, rr = (int)rfl;
            const int c1 = c0 + 1, r1 = rr + 1;

            const bool cv0 = (unsigned)c0 < (unsigned)W;   // 0 <= c0 < W
            const bool cv1 = (unsigned)c1 < (unsigned)W;
            const bool rv0 = (rr >= rlo) & (rr < rhi);     // in-tile (implies 0<=r<H)
            const bool rv1 = (r1 >= rlo) & (r1 < rhi);

            const float omfc = 1.0f - fc, omfr = 1.0f - fr;
            if (rv0) {
                const int ro = (rr - rlo) * W;
                if (cv0) atomicAdd(&smq[ro + c0], w * omfc * omfr);
                if (cv1) atomicAdd(&smq[ro + c1], w * fc   * omfr);
            }
            if (rv1) {
                const int ro = (r1 - rlo) * W;
                if (cv0) atomicAdd(&smq[ro + c0], w * omfc * fr);
                if (cv1) atomicAdd(&smq[ro + c1], w * fc   * fr);
            }
        }
    }
    __syncthreads();

    // write-out: s in [base + r0t*W, +cells), q' in [g0, g0+qw).
    // One float4 global store per (cell, v); LDS gathers are 2 lanes/bank (free).
    const int s0  = base + r0t * W;
    const int nq4 = qw >> 2;                      // 2 (or 1 last group)
    for (int i = tid; i < cells * nq4; i += BLK) {
        const int cell = i / nq4;
        const int v    = i - cell * nq4;
        float4 val;
        val.x = sm[(v * 4 + 0) * MAXC + cell];
        val.y = sm[(v * 4 + 1) * MAXC + cell];
        val.z = sm[(v * 4 + 2) * MAXC + cell];
        val.w = sm[(v * 4 + 3) * MAXC + cell];
        *(float4*)&out[(s0 + cell) * NQ + g0 + v * 4] = val;
    }
}

extern "C" void kernel_launch(void* const* d_in, const int* in_sizes, int n_in,
                              void* d_out, int out_size, void* d_ws, size_t ws_size,
                              hipStream_t stream) {
    const float4* loc4 = (const float4*)d_in[0];  // sampling_locations (fp32), 16B-aligned
    const float4* aw4  = (const float4*)d_in[1];  // attention_weights  (fp32), 16B-aligned
    float* out = (float*)d_out;

    msda_tiled<<<NG * NTILES, BLK, 0, stream>>>(loc4, aw4, out);
}